// Round 1
// baseline (571.335 us; speedup 1.0000x reference)
//
#include <hip/hip_runtime.h>
#include <hip/hip_bf16.h>

// ---------------------------------------------------------------------------
// CausalCrisisLoss on MI355X.
// Key algebra:
//  * cond_mmd needs only group-pair sums GS[gi][gj] = sum_{i,j} Ksum_ij over
//    16 (label x domain) groups -> never materialize the BxB kernel matrix.
//    Gram via bf16 MFMA (diag forced to 5.0, D clamped >=0 so bf16 error
//    cannot blow up exp(-100*D)).
//  * hsic: sum(Kc*Lc) = tr(KL) - (2/n) u^T M v + (u.u)(v.v)/n^2,
//    M = Chat^T Shat (256x256), u = sum_i chat_i, v = sum_i shat_i.
// ---------------------------------------------------------------------------

typedef short bf16x8 __attribute__((ext_vector_type(8)));
typedef float f32x4 __attribute__((ext_vector_type(4)));

static constexpr int D = 256;
static constexpr int H = 768;
static constexpr int NG = 16;

// ---------------------------------------------------------------- detect mask
extern "C" __global__ void k_detect(const unsigned char* mask, int n, float* scal) {
  __shared__ unsigned int sh[3];
  int t = threadIdx.x;
  if (t < 3) sh[t] = 0;
  __syncthreads();
  unsigned int a = 0, b = 0, cd = 0;
  for (int i = t; i < n; i += blockDim.x) {   // first n BYTES: in-bounds for any dtype
    unsigned int v = mask[i];
    int m = i & 3;
    if (m == 0) a |= v; else if (m == 1) b |= v; else cd |= v;
  }
  atomicOr(&sh[0], a); atomicOr(&sh[1], b); atomicOr(&sh[2], cd);
  __syncthreads();
  if (t == 0) {
    int mode;
    if ((sh[1] | sh[2]) == 0) mode = 0;            // int32 0/1
    else if (sh[0] == 0 && sh[1] == 0) mode = 1;   // f32 0.0/1.0
    else mode = 2;                                 // u8 bool
    ((int*)scal)[8] = mode;
  }
}

// ------------------------------------------------------- maskf, gid, counts
extern "C" __global__ __launch_bounds__(256) void k_prep(
    const void* mask, const int* lab1, const int* dom,
    float* scal, float* GC, float* maskf, int* gid, int B) {
  __shared__ float red[4];
  __shared__ float cnt[NG];
  int t = threadIdx.x;
  int r = blockIdx.x * blockDim.x + t;
  if (t < NG) cnt[t] = 0.f;
  __syncthreads();
  int mode = ((const int*)scal)[8];
  float mk = 0.f;
  if (r < B) {
    if (mode == 0)      mk = ((const int*)mask)[r] ? 1.f : 0.f;
    else if (mode == 1) mk = (((const float*)mask)[r] != 0.f) ? 1.f : 0.f;
    else                mk = ((const unsigned char*)mask)[r] ? 1.f : 0.f;
    maskf[r] = mk;
    int g = -1;
    if (mk > 0.f) {
      g = lab1[r] * 4 + dom[r];
      atomicAdd(&cnt[g], 1.f);
    }
    gid[r] = g;
  }
  float v = mk;
  #pragma unroll
  for (int o = 32; o > 0; o >>= 1) v += __shfl_down(v, o);
  if ((t & 63) == 0) red[t >> 6] = v;
  __syncthreads();
  if (t == 0) atomicAdd(&scal[5], red[0] + red[1] + red[2] + red[3]);
  if (t < NG) atomicAdd(&GC[t], cnt[t]);
}

// ------------------------------------- per-row: sq-norm, inv-norm, bf16 copy
extern "C" __global__ void k_rowstats(
    const float* f0, const float* f1, const float* f2, const float* f3,
    unsigned short* bf, float* sq, float* inv, int B) {
  int f = blockIdx.y;
  const float* p = (f == 0) ? f0 : (f == 1) ? f1 : (f == 2) ? f2 : f3;
  int r = blockIdx.x;
  int L = threadIdx.x;                       // 0..63, one wave
  const float4* row = (const float4*)(p + (size_t)r * D);
  float4 v = row[L];
  float ss = v.x * v.x + v.y * v.y + v.z * v.z + v.w * v.w;
  #pragma unroll
  for (int o = 32; o > 0; o >>= 1) ss += __shfl_down(ss, o);
  ss = __shfl(ss, 0);
  if ((f & 1) == 0) {                        // c_v / c_t -> bf16 for MFMA
    int fi = f >> 1;
    alignas(8) __hip_bfloat16 hb[4];
    hb[0] = __float2bfloat16(v.x); hb[1] = __float2bfloat16(v.y);
    hb[2] = __float2bfloat16(v.z); hb[3] = __float2bfloat16(v.w);
    *(uint2*)(bf + ((size_t)fi * B + r) * D + L * 4) = *(uint2*)hb;
    if (L == 0) sq[fi * B + r] = ss;
  }
  if (L == 0) inv[f * B + r] = 1.f / fmaxf(sqrtf(ss), 1e-12f);
}

// ------------------------------------------------------ u = sum_i row_i/|row_i|
extern "C" __global__ __launch_bounds__(256) void k_u(
    const float* f0, const float* f1, const float* f2, const float* f3,
    const float* inv, float* U, int B) {
  int f = blockIdx.y;
  const float* p = (f == 0) ? f0 : (f == 1) ? f1 : (f == 2) ? f2 : f3;
  int t = threadIdx.x;
  int clen = B / gridDim.x;
  int i0 = blockIdx.x * clen;
  float acc = 0.f;
  for (int i = i0; i < i0 + clen; ++i)
    acc += p[(size_t)i * D + t] * inv[f * B + i];
  atomicAdd(&U[f * D + t], acc);
}

// -------------------------------------------------- M = Chat^T Shat (256x256)
extern "C" __global__ __launch_bounds__(256) void k_m(
    const float* cv, const float* sv, const float* ct, const float* st,
    const float* inv, float* M, int B) {
  int p = blockIdx.z;
  const float* c = p ? ct : cv;
  const float* s = p ? st : sv;
  const float* ic = inv + (2 * p) * B;
  const float* is = inv + (2 * p + 1) * B;
  int a0 = blockIdx.x * 16;
  int clen = B / gridDim.y;                  // 512
  int i0 = blockIdx.y * clen;
  __shared__ float lc[512][16];
  int t = threadIdx.x;
  for (int e = t; e < clen * 16; e += 256) {
    int i = e >> 4, r = e & 15;
    lc[i][r] = c[(size_t)(i0 + i) * D + a0 + r] * ic[i0 + i];
  }
  __syncthreads();
  float4 acc[4];
  #pragma unroll
  for (int r = 0; r < 4; ++r) acc[r] = make_float4(0.f, 0.f, 0.f, 0.f);
  for (int i = 0; i < clen; ++i) {
    float svv = s[(size_t)(i0 + i) * D + t] * is[i0 + i];
    const float4* lr = (const float4*)lc[i];
    #pragma unroll
    for (int r = 0; r < 4; ++r) {
      float4 c4 = lr[r];
      acc[r].x += c4.x * svv; acc[r].y += c4.y * svv;
      acc[r].z += c4.z * svv; acc[r].w += c4.w * svv;
    }
  }
  float* Mp = M + (size_t)p * D * D;
  #pragma unroll
  for (int r = 0; r < 4; ++r) {
    atomicAdd(&Mp[(a0 + 4 * r + 0) * D + t], acc[r].x);
    atomicAdd(&Mp[(a0 + 4 * r + 1) * D + t], acc[r].y);
    atomicAdd(&Mp[(a0 + 4 * r + 2) * D + t], acc[r].z);
    atomicAdd(&Mp[(a0 + 4 * r + 3) * D + t], acc[r].w);
  }
}

// --------------------------------------------- MMD: Gram tile + exp + GS accum
// 64x64 output tile per block, triangle-only grid. K staged in halves (2x16KB
// per operand), XOR-swizzled LDS (2-way conflicts only = free on CDNA4).
extern "C" __global__ __launch_bounds__(256) void k_mmd(
    const unsigned short* bf, const float* sq, const int* gid,
    float* GSP, int B) {
  int NT = B / 64;
  int tlin = blockIdx.x;
  int feat = blockIdx.y;
  float tf = (float)tlin;
  int ti = (int)((2.f * NT + 1.f -
                  sqrtf((2.f * NT + 1.f) * (2.f * NT + 1.f) - 8.f * tf)) * 0.5f);
  while (ti > 0 && (ti * NT - (ti * (ti - 1)) / 2) > tlin) --ti;
  while (((ti + 1) * NT - ((ti + 1) * ti) / 2) <= tlin) ++ti;
  int tj = ti + (tlin - (ti * NT - (ti * (ti - 1)) / 2));
  int i0 = ti * 64, j0 = tj * 64;
  const unsigned short* fb = bf + (size_t)feat * B * D;
  const float* sqf = sq + (size_t)feat * B;

  __shared__ alignas(16) unsigned short Ab[64 * 128];
  __shared__ alignas(16) unsigned short Bb[64 * 128];
  __shared__ float gsw[4][NG * NG];

  int tid = threadIdx.x;
  int w = tid >> 6, L = tid & 63, m = L & 15, q = L >> 4;

  f32x4 acc[4] = {{0.f,0.f,0.f,0.f},{0.f,0.f,0.f,0.f},{0.f,0.f,0.f,0.f},{0.f,0.f,0.f,0.f}};

  for (int h = 0; h < 2; ++h) {              // K halves of 128
    if (h) __syncthreads();
    for (int e = tid; e < 1024; e += 256) {
      int row = e >> 4, ck = e & 15;
      uint4 v = *(const uint4*)(fb + (size_t)(i0 + row) * D + h * 128 + ck * 8);
      *(uint4*)&Ab[row * 128 + ((ck ^ (row & 15)) * 8)] = v;
    }
    if (ti != tj) {
      for (int e = tid; e < 1024; e += 256) {
        int row = e >> 4, ck = e & 15;
        uint4 v = *(const uint4*)(fb + (size_t)(j0 + row) * D + h * 128 + ck * 8);
        *(uint4*)&Bb[row * 128 + ((ck ^ (row & 15)) * 8)] = v;
      }
    }
    __syncthreads();
    const unsigned short* Bp = (ti == tj) ? Ab : Bb;
    #pragma unroll
    for (int kk = 0; kk < 4; ++kk) {
      int ar = w * 16 + m;
      bf16x8 aF = *(const bf16x8*)&Ab[ar * 128 + (((kk * 4 + q) ^ (ar & 15)) * 8)];
      #pragma unroll
      for (int c = 0; c < 4; ++c) {
        int br = c * 16 + m;
        bf16x8 bF = *(const bf16x8*)&Bp[br * 128 + (((kk * 4 + q) ^ (br & 15)) * 8)];
        acc[c] = __builtin_amdgcn_mfma_f32_16x16x32_bf16(aF, bF, acc[c], 0, 0, 0);
      }
    }
  }
  __syncthreads();
  for (int e = tid; e < 4 * NG * NG; e += 256) ((float*)gsw)[e] = 0.f;
  __syncthreads();
  // C/D layout (verified m89/m91): col = lane&15, row = (lane>>4)*4 + reg.
  // A transposed-C/D bug would be harmless here (Gram symmetry + double-add).
  #pragma unroll
  for (int c = 0; c < 4; ++c) {
    #pragma unroll
    for (int v = 0; v < 4; ++v) {
      int i = i0 + w * 16 + q * 4 + v;
      int j = j0 + c * 16 + m;
      int gi = gid[i], gj = gid[j];
      if (gi >= 0 && gj >= 0) {
        float K;
        if (i == j) K = 5.f;                 // exact diagonal: 5 gammas * exp(0)
        else {
          float d = sqf[i] + sqf[j] - 2.f * acc[c][v];
          d = fmaxf(d, 0.f);
          K = __expf(-0.01f * d) + __expf(-0.1f * d) + __expf(-d)
            + __expf(-10.f * d) + __expf(-100.f * d);
        }
        atomicAdd(&gsw[w][gi * NG + gj], K);
        if (ti != tj) atomicAdd(&gsw[w][gj * NG + gi], K);
      }
    }
  }
  __syncthreads();
  if (tid < NG * NG) {
    float s = gsw[0][tid] + gsw[1][tid] + gsw[2][tid] + gsw[3][tid];
    if (s != 0.f)   // 64 GS copies to cut global atomic contention 2080 -> ~32
      atomicAdd(&GSP[((size_t)(blockIdx.x & 63) * 2 + feat) * NG * NG + tid], s);
  }
}

// -------------------------------------------------------- focal + CE losses
__device__ inline float focal_n(const float* x, int n, int tgt,
                                float s_over_n, float oms) {
  float mx = x[0];
  for (int c = 1; c < n; ++c) mx = fmaxf(mx, x[c]);
  float se = 0.f, sx = 0.f;
  for (int c = 0; c < n; ++c) { se += __expf(x[c] - mx); sx += x[c]; }
  float logZ = mx + __logf(se);
  float ce = logZ - oms * x[tgt] - s_over_n * sx;
  float pt = __expf(x[tgt] - logZ);
  float om = 1.f - pt;
  return ce * om * om;
}

extern "C" __global__ __launch_bounds__(256) void k_cls(
    const float* l1, const int* y1, const float* l2, const int* y2,
    const float* l3, const int* y3, const float* vsv, const float* vst,
    const int* dom, const float* maskf, float* scal, int B) {
  __shared__ float red[4];
  int t = threadIdx.x;
  int r = blockIdx.x * 256 + t;
  float s[5] = {0.f, 0.f, 0.f, 0.f, 0.f};
  if (r < B) {
    float mk = maskf[r];
    if (mk > 0.f) {
      float x[6];
      for (int c = 0; c < 4; ++c) x[c] = l1[r * 4 + c];
      s[0] = focal_n(x, 4, y1[r], 0.1f / 4.f, 0.9f) * mk;
      for (int c = 0; c < 6; ++c) x[c] = l2[r * 6 + c];
      s[1] = focal_n(x, 6, y2[r], 0.1f / 6.f, 0.9f) * mk;
      for (int c = 0; c < 3; ++c) x[c] = l3[r * 3 + c];
      s[2] = focal_n(x, 3, y3[r], 0.1f / 3.f, 0.9f) * mk;
      int d = dom[r];
      for (int c = 0; c < 4; ++c) x[c] = vsv[r * 4 + c];
      {
        float mx = fmaxf(fmaxf(x[0], x[1]), fmaxf(x[2], x[3]));
        float se = __expf(x[0]-mx) + __expf(x[1]-mx) + __expf(x[2]-mx) + __expf(x[3]-mx);
        s[3] = (mx + __logf(se) - x[d]) * mk;
      }
      for (int c = 0; c < 4; ++c) x[c] = vst[r * 4 + c];
      {
        float mx = fmaxf(fmaxf(x[0], x[1]), fmaxf(x[2], x[3]));
        float se = __expf(x[0]-mx) + __expf(x[1]-mx) + __expf(x[2]-mx) + __expf(x[3]-mx);
        s[4] = (mx + __logf(se) - x[d]) * mk;
      }
    }
  }
  for (int k = 0; k < 5; ++k) {
    float v = s[k];
    #pragma unroll
    for (int o = 32; o > 0; o >>= 1) v += __shfl_down(v, o);
    __syncthreads();
    if ((t & 63) == 0) red[t >> 6] = v;
    __syncthreads();
    if (t == 0) atomicAdd(&scal[k], red[0] + red[1] + red[2] + red[3]);
  }
}

// ------------------------------------------------------------- recon MSE sums
extern "C" __global__ __launch_bounds__(256) void k_recon(
    const float* ir, const float* io, const float* tr_, const float* to,
    float* scal, int N4) {
  __shared__ float red[4];
  int j = blockIdx.y;
  const float4* A  = (const float4*)(j ? tr_ : ir);
  const float4* Bp = (const float4*)(j ? to : io);
  int t = threadIdx.x;
  float acc = 0.f;
  for (int idx = blockIdx.x * 256 + t; idx < N4; idx += gridDim.x * 256) {
    float4 a = A[idx], b = Bp[idx];
    float dx = a.x-b.x, dy = a.y-b.y, dz = a.z-b.z, dw = a.w-b.w;
    acc += dx*dx + dy*dy + dz*dz + dw*dw;
  }
  #pragma unroll
  for (int o = 32; o > 0; o >>= 1) acc += __shfl_down(acc, o);
  if ((t & 63) == 0) red[t >> 6] = acc;
  __syncthreads();
  if (t == 0) atomicAdd(&scal[6 + j], red[0] + red[1] + red[2] + red[3]);
}

// ----------------------------------------------------------------- finalize
extern "C" __global__ __launch_bounds__(256) void k_final(
    const float* scal, const float* GC, const float* GSP,
    const float* U, const float* M, float* out, int B) {
  __shared__ float red[4];
  __shared__ float gssh[2 * NG * NG];
  int t = threadIdx.x;
  for (int e = t; e < 2 * NG * NG; e += 256) {
    float ssum = 0.f;
    int f = e >> 8, idx = e & 255;
    for (int cpy = 0; cpy < 64; ++cpy)
      ssum += GSP[((size_t)cpy * 2 + f) * NG * NG + idx];
    gssh[e] = ssum;
  }
  __syncthreads();

  float n = (float)B;
  float hs[2];
  for (int p = 0; p < 2; ++p) {
    const float* Mp = M + (size_t)p * D * D;
    const float* u = U + (2 * p) * D;
    const float* v = U + (2 * p + 1) * D;
    float trkl = 0.f, cr = 0.f;
    for (int k = 0; k < D; ++k) {
      float mv = Mp[k * D + t];
      trkl += mv * mv;
      cr += u[k] * mv;
    }
    cr *= v[t];
    float sums[4] = {trkl, cr, u[t] * u[t], v[t] * v[t]};
    float res[4];
    for (int k2 = 0; k2 < 4; ++k2) {
      float x = sums[k2];
      #pragma unroll
      for (int o = 32; o > 0; o >>= 1) x += __shfl_down(x, o);
      __syncthreads();
      if ((t & 63) == 0) red[t >> 6] = x;
      __syncthreads();
      res[k2] = red[0] + red[1] + red[2] + red[3];
    }
    hs[p] = (res[0] - (2.f / n) * res[1] + res[2] * res[3] / (n * n))
          / ((n - 1.f) * (n - 1.f));
  }
  if (t == 0) {
    float msum = fmaxf(scal[5], 1.f);
    float f1 = scal[0] / msum, f2 = scal[1] / msum, f3 = scal[2] / msum;
    float cesv = scal[3] / msum, cest = scal[4] / msum;
    float mmd[2];
    for (int f = 0; f < 2; ++f) {
      float loss = 0.f, cntv = 0.f;
      for (int lab = 0; lab < 4; ++lab)
        for (int d1 = 0; d1 < 4; ++d1)
          for (int d2 = d1 + 1; d2 < 4; ++d2) {
            int a = lab * 4 + d1, b = lab * 4 + d2;
            float n1 = GC[a], n2 = GC[b];
            if (n1 > 1.f && n2 > 1.f) {
              float g11 = gssh[f * 256 + a * NG + a];
              float g22 = gssh[f * 256 + b * NG + b];
              float g12 = gssh[f * 256 + a * NG + b];
              loss += g11 / (fmaxf(n1, 1.f) * fmaxf(n1, 1.f))
                    + g22 / (fmaxf(n2, 1.f) * fmaxf(n2, 1.f))
                    - 2.f * g12 / fmaxf(n1 * n2, 1.f);
              cntv += 1.f;
            }
          }
      mmd[f] = loss / fmaxf(cntv, 1.f);
    }
    float recon = (scal[6] + scal[7]) / ((float)B * (float)H);
    float total = 0.4f * f1 + 0.3f * f2 + 0.3f * f3
                + 0.1f * (cesv + cest + mmd[0] + mmd[1])
                + 0.1f * (hs[0] + hs[1])
                + recon;
    out[0] = total;
  }
}

// ---------------------------------------------------------------------------
extern "C" void kernel_launch(void* const* d_in, const int* in_sizes, int n_in,
                              void* d_out, int out_size, void* d_ws, size_t ws_size,
                              hipStream_t stream) {
  const float* l1  = (const float*)d_in[0];
  const int*   y1  = (const int*)d_in[1];
  const float* l2  = (const float*)d_in[2];
  const int*   y2  = (const int*)d_in[3];
  const float* l3  = (const float*)d_in[4];
  const int*   y3  = (const int*)d_in[5];
  const float* cv  = (const float*)d_in[6];
  const float* sv  = (const float*)d_in[7];
  const float* ct  = (const float*)d_in[8];
  const float* st  = (const float*)d_in[9];
  const float* vsv = (const float*)d_in[10];
  const float* vst = (const float*)d_in[11];
  const int*   dom = (const int*)d_in[12];
  const void*  mask= d_in[13];
  const float* ir  = (const float*)d_in[14];
  const float* io  = (const float*)d_in[15];
  const float* trc = (const float*)d_in[16];
  const float* to  = (const float*)d_in[17];
  int B = in_sizes[1];                        // 4096

  // workspace layout (floats)
  float* ws   = (float*)d_ws;
  float* scal = ws + 0;                       // 32  (accumulators + mode int)
  float* GC   = ws + 32;                      // 16
  float* U    = ws + 48;                      // 4*256
  float* M    = ws + 48 + 4 * D;              // 2*256*256
  float* GSP  = M + 2 * D * D;                // 64 copies * 2 * 256
  int zeroFloats = (int)((GSP + 64 * 2 * NG * NG) - ws);
  float* maskf = ws + zeroFloats;             // B
  int*   gid   = (int*)(maskf + B);           // B
  float* sq    = (float*)(gid + B);           // 2*B
  float* inv   = sq + 2 * B;                  // 4*B
  unsigned short* bf = (unsigned short*)(inv + 4 * B); // 2*B*D bf16

  hipMemsetAsync(d_ws, 0, (size_t)zeroFloats * sizeof(float), stream);
  k_detect<<<1, 256, 0, stream>>>((const unsigned char*)mask, B, scal);
  k_prep<<<B / 256, 256, 0, stream>>>(mask, y1, dom, scal, GC, maskf, gid, B);
  k_rowstats<<<dim3(B, 4), 64, 0, stream>>>(cv, sv, ct, st, bf, sq, inv, B);
  k_u<<<dim3(8, 4), 256, 0, stream>>>(cv, sv, ct, st, inv, U, B);
  k_m<<<dim3(16, 8, 2), 256, 0, stream>>>(cv, sv, ct, st, inv, M, B);
  int NT = B / 64;
  k_mmd<<<dim3(NT * (NT + 1) / 2, 2), 256, 0, stream>>>(bf, sq, gid, GSP, B);
  k_cls<<<B / 256, 256, 0, stream>>>(l1, y1, l2, y2, l3, y3, vsv, vst, dom,
                                     maskf, scal, B);
  k_recon<<<dim3(1024, 2), 256, 0, stream>>>(ir, io, trc, to, scal, B * H / 4);
  k_final<<<1, 256, 0, stream>>>(scal, GC, GSP, U, M, (float*)d_out, B);
}

// Round 2
// 443.765 us; speedup vs baseline: 1.2875x; 1.2875x over previous
//
#include <hip/hip_runtime.h>
#include <hip/hip_bf16.h>

// ---------------------------------------------------------------------------
// CausalCrisisLoss on MI355X.  R2: eliminate ALL float atomics (they expand to
// CAS loops without -munsafe-fp-atomics -> 300cyc dependent chains x retries;
// R1 showed k_mmd 208us with all pipes <11% busy = latency-serialized).
//  * LDS histograms: u32 fixed-point (x2^16), native ds_add_u32.
//  * Global accumulators: i64 fixed-point (x2^32), native u64 atomicAdd.
//  * k_mmd caches gid/sq per tile in LDS (removes 32 scattered loads/thread).
// ---------------------------------------------------------------------------

typedef short bf16x8 __attribute__((ext_vector_type(8)));
typedef float f32x4 __attribute__((ext_vector_type(4)));
typedef unsigned long long u64;

static constexpr int D = 256;
static constexpr int H = 768;
static constexpr int NG = 16;
static constexpr float FX32 = 4294967296.f;       // 2^32
static constexpr float IFX32 = 2.3283064365386963e-10f;

__device__ inline void gAddFx(u64* p, float v) {  // exact cross-block accum
  long long q = (long long)llroundf(v * FX32);
  atomicAdd(p, (u64)q);                           // native global_atomic_add_x2
}

// ---------------------------------------------------------------- detect mask
extern "C" __global__ void k_detect(const unsigned char* mask, int n, u64* SA) {
  __shared__ unsigned int sh[3];
  int t = threadIdx.x;
  if (t < 3) sh[t] = 0;
  __syncthreads();
  unsigned int a = 0, b = 0, cd = 0;
  for (int i = t; i < n; i += blockDim.x) {   // first n BYTES: in-bounds for any dtype
    unsigned int v = mask[i];
    int m = i & 3;
    if (m == 0) a |= v; else if (m == 1) b |= v; else cd |= v;
  }
  atomicOr(&sh[0], a); atomicOr(&sh[1], b); atomicOr(&sh[2], cd);
  __syncthreads();
  if (t == 0) {
    unsigned int mode;
    if ((sh[1] | sh[2]) == 0) mode = 0;            // int32 0/1
    else if (sh[0] == 0 && sh[1] == 0) mode = 1;   // f32 0.0/1.0
    else mode = 2;                                 // u8 bool
    ((unsigned int*)(SA + 8))[0] = mode;
  }
}

// ------------------------------------------------------- maskf, gid, counts
extern "C" __global__ __launch_bounds__(256) void k_prep(
    const void* mask, const int* lab1, const int* dom,
    u64* SA, u64* GCU, float* maskf, int* gid, int B) {
  __shared__ int redi[4];
  __shared__ unsigned int cnt[NG];
  int t = threadIdx.x;
  int r = blockIdx.x * blockDim.x + t;
  if (t < NG) cnt[t] = 0;
  __syncthreads();
  unsigned int mode = ((const unsigned int*)(SA + 8))[0];
  int mi = 0;
  if (r < B) {
    if (mode == 0)      mi = ((const int*)mask)[r] ? 1 : 0;
    else if (mode == 1) mi = (((const float*)mask)[r] != 0.f) ? 1 : 0;
    else                mi = ((const unsigned char*)mask)[r] ? 1 : 0;
    maskf[r] = (float)mi;
    int g = -1;
    if (mi) {
      g = lab1[r] * 4 + dom[r];
      atomicAdd(&cnt[g], 1u);                 // native ds_add_u32
    }
    gid[r] = g;
  }
  int v = mi;
  #pragma unroll
  for (int o = 32; o > 0; o >>= 1) v += __shfl_down(v, o);
  if ((t & 63) == 0) redi[t >> 6] = v;
  __syncthreads();
  if (t == 0) atomicAdd(&SA[5], (u64)(redi[0] + redi[1] + redi[2] + redi[3]));
  if (t < NG) atomicAdd(&GCU[t], (u64)cnt[t]);
}

// ------------------------------------- per-row: sq-norm, inv-norm, bf16 copy
extern "C" __global__ void k_rowstats(
    const float* f0, const float* f1, const float* f2, const float* f3,
    unsigned short* bf, float* sq, float* inv, int B) {
  int f = blockIdx.y;
  const float* p = (f == 0) ? f0 : (f == 1) ? f1 : (f == 2) ? f2 : f3;
  int r = blockIdx.x;
  int L = threadIdx.x;                       // 0..63, one wave
  const float4* row = (const float4*)(p + (size_t)r * D);
  float4 v = row[L];
  float ss = v.x * v.x + v.y * v.y + v.z * v.z + v.w * v.w;
  #pragma unroll
  for (int o = 32; o > 0; o >>= 1) ss += __shfl_down(ss, o);
  ss = __shfl(ss, 0);
  if ((f & 1) == 0) {                        // c_v / c_t -> bf16 for MFMA
    int fi = f >> 1;
    alignas(8) __hip_bfloat16 hb[4];
    hb[0] = __float2bfloat16(v.x); hb[1] = __float2bfloat16(v.y);
    hb[2] = __float2bfloat16(v.z); hb[3] = __float2bfloat16(v.w);
    *(uint2*)(bf + ((size_t)fi * B + r) * D + L * 4) = *(uint2*)hb;
    if (L == 0) sq[fi * B + r] = ss;
  }
  if (L == 0) inv[f * B + r] = 1.f / fmaxf(sqrtf(ss), 1e-12f);
}

// ------------------------------------------------------ u = sum_i row_i/|row_i|
extern "C" __global__ __launch_bounds__(256) void k_u(
    const float* f0, const float* f1, const float* f2, const float* f3,
    const float* inv, u64* U64, int B) {
  int f = blockIdx.y;
  const float* p = (f == 0) ? f0 : (f == 1) ? f1 : (f == 2) ? f2 : f3;
  int t = threadIdx.x;
  int clen = B / gridDim.x;
  int i0 = blockIdx.x * clen;
  float acc = 0.f;
  for (int i = i0; i < i0 + clen; ++i)
    acc += p[(size_t)i * D + t] * inv[f * B + i];
  gAddFx(&U64[f * D + t], acc);
}

// -------------------------------------------------- M = Chat^T Shat (256x256)
extern "C" __global__ __launch_bounds__(256) void k_m(
    const float* cv, const float* sv, const float* ct, const float* st,
    const float* inv, u64* M64, int B) {
  int p = blockIdx.z;
  const float* c = p ? ct : cv;
  const float* s = p ? st : sv;
  const float* ic = inv + (2 * p) * B;
  const float* is = inv + (2 * p + 1) * B;
  int a0 = blockIdx.x * 16;
  int clen = B / gridDim.y;                  // 512
  int i0 = blockIdx.y * clen;
  __shared__ float lc[512][16];
  int t = threadIdx.x;
  for (int e = t; e < clen * 16; e += 256) {
    int i = e >> 4, r = e & 15;
    lc[i][r] = c[(size_t)(i0 + i) * D + a0 + r] * ic[i0 + i];
  }
  __syncthreads();
  float4 acc[4];
  #pragma unroll
  for (int r = 0; r < 4; ++r) acc[r] = make_float4(0.f, 0.f, 0.f, 0.f);
  for (int i = 0; i < clen; ++i) {
    float svv = s[(size_t)(i0 + i) * D + t] * is[i0 + i];
    const float4* lr = (const float4*)lc[i];
    #pragma unroll
    for (int r = 0; r < 4; ++r) {
      float4 c4 = lr[r];
      acc[r].x += c4.x * svv; acc[r].y += c4.y * svv;
      acc[r].z += c4.z * svv; acc[r].w += c4.w * svv;
    }
  }
  u64* Mp = M64 + (size_t)p * D * D;
  #pragma unroll
  for (int r = 0; r < 4; ++r) {
    gAddFx(&Mp[(a0 + 4 * r + 0) * D + t], acc[r].x);
    gAddFx(&Mp[(a0 + 4 * r + 1) * D + t], acc[r].y);
    gAddFx(&Mp[(a0 + 4 * r + 2) * D + t], acc[r].z);
    gAddFx(&Mp[(a0 + 4 * r + 3) * D + t], acc[r].w);
  }
}

// --------------------------------------------- MMD: Gram tile + exp + GS accum
// 64x64 output tile per block, triangle-only grid. Histogram in u32 fixed
// point (x2^16) via native ds_add_u32; block partial -> u64 global atomic.
extern "C" __global__ __launch_bounds__(256) void k_mmd(
    const unsigned short* bf, const float* sq, const int* gid,
    u64* GSP, int B) {
  int NT = B / 64;
  int tlin = blockIdx.x;
  int feat = blockIdx.y;
  float tf = (float)tlin;
  int ti = (int)((2.f * NT + 1.f -
                  sqrtf((2.f * NT + 1.f) * (2.f * NT + 1.f) - 8.f * tf)) * 0.5f);
  while (ti > 0 && (ti * NT - (ti * (ti - 1)) / 2) > tlin) --ti;
  while (((ti + 1) * NT - ((ti + 1) * ti) / 2) <= tlin) ++ti;
  int tj = ti + (tlin - (ti * NT - (ti * (ti - 1)) / 2));
  int i0 = ti * 64, j0 = tj * 64;
  const unsigned short* fb = bf + (size_t)feat * B * D;
  const float* sqf = sq + (size_t)feat * B;

  __shared__ alignas(16) unsigned short Ab[64 * 128];
  __shared__ alignas(16) unsigned short Bb[64 * 128];
  __shared__ unsigned int gsw[4][NG * NG];
  __shared__ int gA[64], gB[64];
  __shared__ float sA[64], sB[64];

  int tid = threadIdx.x;
  int w = tid >> 6, L = tid & 63, m = L & 15, q = L >> 4;

  // prologue (pre-barrier): zero histogram, cache tile gid/sq in LDS
  {
    unsigned int* gz = (unsigned int*)gsw;
    #pragma unroll
    for (int e = 0; e < 4; ++e) gz[tid + 256 * e] = 0;
    if (tid < 64) { gA[tid] = gid[i0 + tid]; sA[tid] = sqf[i0 + tid]; }
    else if (tid < 128) { int r = tid - 64; gB[r] = gid[j0 + r]; sB[r] = sqf[j0 + r]; }
  }

  f32x4 acc[4] = {{0.f,0.f,0.f,0.f},{0.f,0.f,0.f,0.f},{0.f,0.f,0.f,0.f},{0.f,0.f,0.f,0.f}};

  for (int h = 0; h < 2; ++h) {              // K halves of 128
    if (h) __syncthreads();
    for (int e = tid; e < 1024; e += 256) {
      int row = e >> 4, ck = e & 15;
      uint4 v = *(const uint4*)(fb + (size_t)(i0 + row) * D + h * 128 + ck * 8);
      *(uint4*)&Ab[row * 128 + ((ck ^ (row & 15)) * 8)] = v;
    }
    if (ti != tj) {
      for (int e = tid; e < 1024; e += 256) {
        int row = e >> 4, ck = e & 15;
        uint4 v = *(const uint4*)(fb + (size_t)(j0 + row) * D + h * 128 + ck * 8);
        *(uint4*)&Bb[row * 128 + ((ck ^ (row & 15)) * 8)] = v;
      }
    }
    __syncthreads();
    const unsigned short* Bp = (ti == tj) ? Ab : Bb;
    #pragma unroll
    for (int kk = 0; kk < 4; ++kk) {
      int ar = w * 16 + m;
      bf16x8 aF = *(const bf16x8*)&Ab[ar * 128 + (((kk * 4 + q) ^ (ar & 15)) * 8)];
      #pragma unroll
      for (int c = 0; c < 4; ++c) {
        int br = c * 16 + m;
        bf16x8 bF = *(const bf16x8*)&Bp[br * 128 + (((kk * 4 + q) ^ (br & 15)) * 8)];
        acc[c] = __builtin_amdgcn_mfma_f32_16x16x32_bf16(aF, bF, acc[c], 0, 0, 0);
      }
    }
  }
  // C/D layout (verified m89/m91): col = lane&15, row = (lane>>4)*4 + reg.
  // No barrier needed: wave w writes only gsw[w]; gA/sA/gsw written pre-barrier.
  #pragma unroll
  for (int c = 0; c < 4; ++c) {
    #pragma unroll
    for (int v = 0; v < 4; ++v) {
      int ri = w * 16 + q * 4 + v;           // row in tile
      int rj = c * 16 + m;                   // col in tile
      int gi = gA[ri], gj = gB[rj];
      if (gi >= 0 && gj >= 0) {
        float K;
        if (i0 + ri == j0 + rj) K = 5.f;     // exact diagonal
        else {
          float d = sA[ri] + sB[rj] - 2.f * acc[c][v];
          d = fmaxf(d, 0.f);
          K = __expf(-0.01f * d) + __expf(-0.1f * d) + __expf(-d)
            + __expf(-10.f * d) + __expf(-100.f * d);
        }
        unsigned int kf = (unsigned int)(K * 65536.f + 0.5f);
        atomicAdd(&gsw[w][gi * NG + gj], kf);              // ds_add_u32
        if (ti != tj) atomicAdd(&gsw[w][gj * NG + gi], kf);
      }
    }
  }
  __syncthreads();
  if (tid < NG * NG) {
    u64 s = (u64)gsw[0][tid] + gsw[1][tid] + gsw[2][tid] + gsw[3][tid];
    if (s)   // 64 GSP copies to spread global atomic contention
      atomicAdd(&GSP[((size_t)(blockIdx.x & 63) * 2 + feat) * NG * NG + tid], s);
  }
}

// -------------------------------------------------------- focal + CE losses
__device__ inline float focal_n(const float* x, int n, int tgt,
                                float s_over_n, float oms) {
  float mx = x[0];
  for (int c = 1; c < n; ++c) mx = fmaxf(mx, x[c]);
  float se = 0.f, sx = 0.f;
  for (int c = 0; c < n; ++c) { se += __expf(x[c] - mx); sx += x[c]; }
  float logZ = mx + __logf(se);
  float ce = logZ - oms * x[tgt] - s_over_n * sx;
  float pt = __expf(x[tgt] - logZ);
  float om = 1.f - pt;
  return ce * om * om;
}

extern "C" __global__ __launch_bounds__(256) void k_cls(
    const float* l1, const int* y1, const float* l2, const int* y2,
    const float* l3, const int* y3, const float* vsv, const float* vst,
    const int* dom, const float* maskf, u64* SA, int B) {
  __shared__ float red[4];
  int t = threadIdx.x;
  int r = blockIdx.x * 256 + t;
  float s[5] = {0.f, 0.f, 0.f, 0.f, 0.f};
  if (r < B) {
    float mk = maskf[r];
    if (mk > 0.f) {
      float x[6];
      for (int c = 0; c < 4; ++c) x[c] = l1[r * 4 + c];
      s[0] = focal_n(x, 4, y1[r], 0.1f / 4.f, 0.9f) * mk;
      for (int c = 0; c < 6; ++c) x[c] = l2[r * 6 + c];
      s[1] = focal_n(x, 6, y2[r], 0.1f / 6.f, 0.9f) * mk;
      for (int c = 0; c < 3; ++c) x[c] = l3[r * 3 + c];
      s[2] = focal_n(x, 3, y3[r], 0.1f / 3.f, 0.9f) * mk;
      int d = dom[r];
      for (int c = 0; c < 4; ++c) x[c] = vsv[r * 4 + c];
      {
        float mx = fmaxf(fmaxf(x[0], x[1]), fmaxf(x[2], x[3]));
        float se = __expf(x[0]-mx) + __expf(x[1]-mx) + __expf(x[2]-mx) + __expf(x[3]-mx);
        s[3] = (mx + __logf(se) - x[d]) * mk;
      }
      for (int c = 0; c < 4; ++c) x[c] = vst[r * 4 + c];
      {
        float mx = fmaxf(fmaxf(x[0], x[1]), fmaxf(x[2], x[3]));
        float se = __expf(x[0]-mx) + __expf(x[1]-mx) + __expf(x[2]-mx) + __expf(x[3]-mx);
        s[4] = (mx + __logf(se) - x[d]) * mk;
      }
    }
  }
  for (int k = 0; k < 5; ++k) {
    float v = s[k];
    #pragma unroll
    for (int o = 32; o > 0; o >>= 1) v += __shfl_down(v, o);
    __syncthreads();
    if ((t & 63) == 0) red[t >> 6] = v;
    __syncthreads();
    if (t == 0) gAddFx(&SA[k], red[0] + red[1] + red[2] + red[3]);
  }
}

// ------------------------------------------------------------- recon MSE sums
extern "C" __global__ __launch_bounds__(256) void k_recon(
    const float* ir, const float* io, const float* tr_, const float* to,
    u64* SA, int N4) {
  __shared__ float red[4];
  int j = blockIdx.y;
  const float4* A  = (const float4*)(j ? tr_ : ir);
  const float4* Bp = (const float4*)(j ? to : io);
  int t = threadIdx.x;
  float acc = 0.f;
  for (int idx = blockIdx.x * 256 + t; idx < N4; idx += gridDim.x * 256) {
    float4 a = A[idx], b = Bp[idx];
    float dx = a.x-b.x, dy = a.y-b.y, dz = a.z-b.z, dw = a.w-b.w;
    acc += dx*dx + dy*dy + dz*dz + dw*dw;
  }
  #pragma unroll
  for (int o = 32; o > 0; o >>= 1) acc += __shfl_down(acc, o);
  if ((t & 63) == 0) red[t >> 6] = acc;
  __syncthreads();
  if (t == 0) gAddFx(&SA[6 + j], red[0] + red[1] + red[2] + red[3]);
}

// ----------------------------------------------------------------- finalize
extern "C" __global__ __launch_bounds__(256) void k_final(
    const u64* SA, const u64* GCU, const u64* GSP,
    const u64* U64, const u64* M64, float* out, int B) {
  __shared__ float red[4];
  __shared__ float gssh[2 * NG * NG];
  __shared__ float usg[D], vsg[D];
  int t = threadIdx.x;
  for (int e = t; e < 2 * NG * NG; e += 256) {
    u64 ssum = 0;
    int f = e >> 8, idx = e & 255;
    for (int cpy = 0; cpy < 64; ++cpy)
      ssum += GSP[((size_t)cpy * 2 + f) * NG * NG + idx];
    gssh[e] = (float)((double)ssum * (1.0 / 65536.0));
  }
  __syncthreads();

  float n = (float)B;
  float hs[2];
  for (int p = 0; p < 2; ++p) {
    const u64* Mp = M64 + (size_t)p * D * D;
    usg[t] = (float)(long long)U64[(2 * p) * D + t] * IFX32;
    vsg[t] = (float)(long long)U64[(2 * p + 1) * D + t] * IFX32;
    __syncthreads();
    float trkl = 0.f, cr = 0.f;
    for (int k = 0; k < D; ++k) {
      float mv = (float)(long long)Mp[k * D + t] * IFX32;
      trkl += mv * mv;
      cr += usg[k] * mv;
    }
    cr *= vsg[t];
    float sums[4] = {trkl, cr, usg[t] * usg[t], vsg[t] * vsg[t]};
    float res[4];
    for (int k2 = 0; k2 < 4; ++k2) {
      float x = sums[k2];
      #pragma unroll
      for (int o = 32; o > 0; o >>= 1) x += __shfl_down(x, o);
      __syncthreads();
      if ((t & 63) == 0) red[t >> 6] = x;
      __syncthreads();
      res[k2] = red[0] + red[1] + red[2] + red[3];
    }
    hs[p] = (res[0] - (2.f / n) * res[1] + res[2] * res[3] / (n * n))
          / ((n - 1.f) * (n - 1.f));
    __syncthreads();
  }
  if (t == 0) {
    float msum = fmaxf((float)SA[5], 1.f);
    float f1 = (float)(long long)SA[0] * IFX32 / msum;
    float f2 = (float)(long long)SA[1] * IFX32 / msum;
    float f3 = (float)(long long)SA[2] * IFX32 / msum;
    float cesv = (float)(long long)SA[3] * IFX32 / msum;
    float cest = (float)(long long)SA[4] * IFX32 / msum;
    float mmd[2];
    for (int f = 0; f < 2; ++f) {
      float loss = 0.f, cntv = 0.f;
      for (int lab = 0; lab < 4; ++lab)
        for (int d1 = 0; d1 < 4; ++d1)
          for (int d2 = d1 + 1; d2 < 4; ++d2) {
            int a = lab * 4 + d1, b = lab * 4 + d2;
            float n1 = (float)GCU[a], n2 = (float)GCU[b];
            if (n1 > 1.f && n2 > 1.f) {
              float g11 = gssh[f * 256 + a * NG + a];
              float g22 = gssh[f * 256 + b * NG + b];
              float g12 = gssh[f * 256 + a * NG + b];
              loss += g11 / (fmaxf(n1, 1.f) * fmaxf(n1, 1.f))
                    + g22 / (fmaxf(n2, 1.f) * fmaxf(n2, 1.f))
                    - 2.f * g12 / fmaxf(n1 * n2, 1.f);
              cntv += 1.f;
            }
          }
      mmd[f] = loss / fmaxf(cntv, 1.f);
    }
    double rs = ((double)(long long)SA[6] + (double)(long long)SA[7])
              * (double)IFX32;
    float recon = (float)(rs / ((double)B * (double)H));
    float total = 0.4f * f1 + 0.3f * f2 + 0.3f * f3
                + 0.1f * (cesv + cest + mmd[0] + mmd[1])
                + 0.1f * (hs[0] + hs[1])
                + recon;
    out[0] = total;
  }
}

// ---------------------------------------------------------------------------
extern "C" void kernel_launch(void* const* d_in, const int* in_sizes, int n_in,
                              void* d_out, int out_size, void* d_ws, size_t ws_size,
                              hipStream_t stream) {
  const float* l1  = (const float*)d_in[0];
  const int*   y1  = (const int*)d_in[1];
  const float* l2  = (const float*)d_in[2];
  const int*   y2  = (const int*)d_in[3];
  const float* l3  = (const float*)d_in[4];
  const int*   y3  = (const int*)d_in[5];
  const float* cv  = (const float*)d_in[6];
  const float* sv  = (const float*)d_in[7];
  const float* ct  = (const float*)d_in[8];
  const float* st  = (const float*)d_in[9];
  const float* vsv = (const float*)d_in[10];
  const float* vst = (const float*)d_in[11];
  const int*   dom = (const int*)d_in[12];
  const void*  mask= d_in[13];
  const float* ir  = (const float*)d_in[14];
  const float* io  = (const float*)d_in[15];
  const float* trc = (const float*)d_in[16];
  const float* to  = (const float*)d_in[17];
  int B = in_sizes[1];                        // 4096

  // workspace layout: u64 accumulators first (all zeroed), then scratch
  u64* SA  = (u64*)d_ws;                      // 32 slots (cls/msum/recon/mode)
  u64* GCU = SA + 32;                         // 16 group counts
  u64* U64 = GCU + 16;                        // 4*256  (i64 fx 2^32)
  u64* M64 = U64 + 4 * D;                     // 2*256*256 (i64 fx 2^32)
  u64* GSP = M64 + 2 * D * D;                 // 64*2*256 (u64 fx 2^16)
  u64* zend = GSP + 64 * 2 * NG * NG;
  size_t zeroBytes = (size_t)((char*)zend - (char*)d_ws);
  float* maskf = (float*)zend;                // B
  int*   gid   = (int*)(maskf + B);           // B
  float* sq    = (float*)(gid + B);           // 2*B
  float* inv   = sq + 2 * B;                  // 4*B
  unsigned short* bf = (unsigned short*)(inv + 4 * B); // 2*B*D bf16

  hipMemsetAsync(d_ws, 0, zeroBytes, stream);
  k_detect<<<1, 256, 0, stream>>>((const unsigned char*)mask, B, SA);
  k_prep<<<B / 256, 256, 0, stream>>>(mask, y1, dom, SA, GCU, maskf, gid, B);
  k_rowstats<<<dim3(B, 4), 64, 0, stream>>>(cv, sv, ct, st, bf, sq, inv, B);
  k_u<<<dim3(8, 4), 256, 0, stream>>>(cv, sv, ct, st, inv, U64, B);
  k_m<<<dim3(16, 8, 2), 256, 0, stream>>>(cv, sv, ct, st, inv, M64, B);
  int NT = B / 64;
  k_mmd<<<dim3(NT * (NT + 1) / 2, 2), 256, 0, stream>>>(bf, sq, gid, GSP, B);
  k_cls<<<B / 256, 256, 0, stream>>>(l1, y1, l2, y2, l3, y3, vsv, vst, dom,
                                     maskf, SA, B);
  k_recon<<<dim3(1024, 2), 256, 0, stream>>>(ir, io, trc, to, SA, B * H / 4);
  k_final<<<1, 256, 0, stream>>>(SA, GCU, GSP, U64, M64, (float*)d_out, B);
}

// Round 3
// 315.852 us; speedup vs baseline: 1.8089x; 1.4050x over previous
//
#include <hip/hip_runtime.h>
#include <hip/hip_bf16.h>

// ---------------------------------------------------------------------------
// CausalCrisisLoss on MI355X.  R3:
//  * k_u was 120us latency-serialized (512-iter dependent-load loop, 32
//    blocks). Rewritten: 256 blocks x 64 rows, inv staged in LDS, unroll 8.
//  * k_mmd epilogue: canonical unordered bins (K symmetric, diag==5.0 exact)
//    -> half the LDS atomics; per-(wave,quad) sub-histograms kill most
//    same-address collisions. S[a][a] = 2*bin - 5*n_a reconstructed at end.
//  * hsic M-reduction moved out of single-block k_final into k_hsic.
//  * No float atomics anywhere (they expand to CAS loops): u32 ds_add +
//    i64 fixed-point global atomics.
// ---------------------------------------------------------------------------

typedef short bf16x8 __attribute__((ext_vector_type(8)));
typedef float f32x4 __attribute__((ext_vector_type(4)));
typedef unsigned long long u64;

static constexpr int D = 256;
static constexpr int H = 768;
static constexpr int NG = 16;
static constexpr int HS = 264;                    // sub-histogram stride (bank skew 8)
static constexpr float FX32 = 4294967296.f;       // 2^32
static constexpr float IFX32 = 2.3283064365386963e-10f;

__device__ inline void gAddFx(u64* p, float v) {  // exact cross-block accum
  long long q = (long long)llroundf(v * FX32);
  atomicAdd(p, (u64)q);                           // native global_atomic_add_x2
}
__device__ inline float fxToF(u64 v) { return (float)(long long)v * IFX32; }

// ---------------------------------------------------------------- detect mask
extern "C" __global__ void k_detect(const unsigned char* mask, int n, u64* SA) {
  __shared__ unsigned int sh[3];
  int t = threadIdx.x;
  if (t < 3) sh[t] = 0;
  __syncthreads();
  unsigned int a = 0, b = 0, cd = 0;
  for (int i = t; i < n; i += blockDim.x) {   // first n BYTES: in-bounds for any dtype
    unsigned int v = mask[i];
    int m = i & 3;
    if (m == 0) a |= v; else if (m == 1) b |= v; else cd |= v;
  }
  atomicOr(&sh[0], a); atomicOr(&sh[1], b); atomicOr(&sh[2], cd);
  __syncthreads();
  if (t == 0) {
    unsigned int mode;
    if ((sh[1] | sh[2]) == 0) mode = 0;            // int32 0/1
    else if (sh[0] == 0 && sh[1] == 0) mode = 1;   // f32 0.0/1.0
    else mode = 2;                                 // u8 bool
    ((unsigned int*)(SA + 8))[0] = mode;
  }
}

// ------------------------------------------------------- maskf, gid, counts
extern "C" __global__ __launch_bounds__(256) void k_prep(
    const void* mask, const int* lab1, const int* dom,
    u64* SA, u64* GCU, float* maskf, int* gid, int B) {
  __shared__ int redi[4];
  __shared__ unsigned int cnt[NG];
  int t = threadIdx.x;
  int r = blockIdx.x * blockDim.x + t;
  if (t < NG) cnt[t] = 0;
  __syncthreads();
  unsigned int mode = ((const unsigned int*)(SA + 8))[0];
  int mi = 0;
  if (r < B) {
    if (mode == 0)      mi = ((const int*)mask)[r] ? 1 : 0;
    else if (mode == 1) mi = (((const float*)mask)[r] != 0.f) ? 1 : 0;
    else                mi = ((const unsigned char*)mask)[r] ? 1 : 0;
    maskf[r] = (float)mi;
    int g = -1;
    if (mi) {
      g = lab1[r] * 4 + dom[r];
      atomicAdd(&cnt[g], 1u);                 // native ds_add_u32
    }
    gid[r] = g;
  }
  int v = mi;
  #pragma unroll
  for (int o = 32; o > 0; o >>= 1) v += __shfl_down(v, o);
  if ((t & 63) == 0) redi[t >> 6] = v;
  __syncthreads();
  if (t == 0) atomicAdd(&SA[5], (u64)(redi[0] + redi[1] + redi[2] + redi[3]));
  if (t < NG) atomicAdd(&GCU[t], (u64)cnt[t]);
}

// ------------------------------------- per-row: sq-norm, inv-norm, bf16 copy
extern "C" __global__ __launch_bounds__(256) void k_rowstats(
    const float* __restrict__ f0, const float* __restrict__ f1,
    const float* __restrict__ f2, const float* __restrict__ f3,
    unsigned short* bf, float* sq, float* inv, int B) {
  int f = blockIdx.y;
  const float* p = (f == 0) ? f0 : (f == 1) ? f1 : (f == 2) ? f2 : f3;
  int w = threadIdx.x >> 6;
  int r = blockIdx.x * 4 + w;                // 4 waves = 4 rows per block
  int L = threadIdx.x & 63;
  const float4* row = (const float4*)(p + (size_t)r * D);
  float4 v = row[L];
  float ss = v.x * v.x + v.y * v.y + v.z * v.z + v.w * v.w;
  #pragma unroll
  for (int o = 32; o > 0; o >>= 1) ss += __shfl_down(ss, o);
  ss = __shfl(ss, 0);
  if ((f & 1) == 0) {                        // c_v / c_t -> bf16 for MFMA
    int fi = f >> 1;
    alignas(8) __hip_bfloat16 hb[4];
    hb[0] = __float2bfloat16(v.x); hb[1] = __float2bfloat16(v.y);
    hb[2] = __float2bfloat16(v.z); hb[3] = __float2bfloat16(v.w);
    *(uint2*)(bf + ((size_t)fi * B + r) * D + L * 4) = *(uint2*)hb;
    if (L == 0) sq[fi * B + r] = ss;
  }
  if (L == 0) inv[f * B + r] = 1.f / fmaxf(sqrtf(ss), 1e-12f);
}

// ------------------------------------------------------ u = sum_i row_i/|row_i|
extern "C" __global__ __launch_bounds__(256) void k_u(
    const float* __restrict__ f0, const float* __restrict__ f1,
    const float* __restrict__ f2, const float* __restrict__ f3,
    const float* __restrict__ inv, u64* U64, int B) {
  int f = blockIdx.y;
  const float* p = (f == 0) ? f0 : (f == 1) ? f1 : (f == 2) ? f2 : f3;
  int t = threadIdx.x;
  int i0 = blockIdx.x * 64;                  // 64 rows per block
  __shared__ float linv[64];
  if (t < 64) linv[t] = inv[f * B + i0 + t];
  __syncthreads();
  float acc = 0.f;
  #pragma unroll 8
  for (int i = 0; i < 64; ++i)
    acc += p[(size_t)(i0 + i) * D + t] * linv[i];
  gAddFx(&U64[f * D + t], acc);
}

// -------------------------------------------------- M = Chat^T Shat (256x256)
extern "C" __global__ __launch_bounds__(256) void k_m(
    const float* __restrict__ cv, const float* __restrict__ sv,
    const float* __restrict__ ct, const float* __restrict__ st,
    const float* __restrict__ inv, u64* M64, int B) {
  int p = blockIdx.z;
  const float* c = p ? ct : cv;
  const float* s = p ? st : sv;
  const float* ic = inv + (2 * p) * B;
  const float* is = inv + (2 * p + 1) * B;
  int a0 = blockIdx.x * 16;
  int clen = B / gridDim.y;                  // 512
  int i0 = blockIdx.y * clen;
  __shared__ float lc[512][16];
  __shared__ float lis[512];
  int t = threadIdx.x;
  for (int e = t; e < clen; e += 256) lis[e] = is[i0 + e];
  for (int e = t; e < clen * 16; e += 256) {
    int i = e >> 4, r = e & 15;
    lc[i][r] = c[(size_t)(i0 + i) * D + a0 + r] * ic[i0 + i];
  }
  __syncthreads();
  float4 acc[4];
  #pragma unroll
  for (int r = 0; r < 4; ++r) acc[r] = make_float4(0.f, 0.f, 0.f, 0.f);
  #pragma unroll 4
  for (int i = 0; i < 512; ++i) {
    float svv = s[(size_t)(i0 + i) * D + t] * lis[i];
    const float4* lr = (const float4*)lc[i];
    #pragma unroll
    for (int r = 0; r < 4; ++r) {
      float4 c4 = lr[r];
      acc[r].x += c4.x * svv; acc[r].y += c4.y * svv;
      acc[r].z += c4.z * svv; acc[r].w += c4.w * svv;
    }
  }
  u64* Mp = M64 + (size_t)p * D * D;
  #pragma unroll
  for (int r = 0; r < 4; ++r) {
    gAddFx(&Mp[(a0 + 4 * r + 0) * D + t], acc[r].x);
    gAddFx(&Mp[(a0 + 4 * r + 1) * D + t], acc[r].y);
    gAddFx(&Mp[(a0 + 4 * r + 2) * D + t], acc[r].z);
    gAddFx(&Mp[(a0 + 4 * r + 3) * D + t], acc[r].w);
  }
}

// --------------------------------------------- MMD: Gram tile + exp + GS accum
// 64x64 tile per block, triangle grid. Canonical unordered bins: each
// unordered element pair counted ONCE into bin[min(g)][max(g)] (diag tiles
// skip ri>rj). Reconstruction in k_final: S[a][b]=bin, S[a][a]=2*bin-5*n_a.
// Per-(wave,quad) u32 sub-histograms (stride 264 -> bank skew) via ds_add_u32.
extern "C" __global__ __launch_bounds__(256) void k_mmd(
    const unsigned short* __restrict__ bf, const float* __restrict__ sq,
    const int* __restrict__ gid, u64* GSP, int B) {
  int NT = B / 64;
  int tlin = blockIdx.x;
  int feat = blockIdx.y;
  float tf = (float)tlin;
  int ti = (int)((2.f * NT + 1.f -
                  sqrtf((2.f * NT + 1.f) * (2.f * NT + 1.f) - 8.f * tf)) * 0.5f);
  while (ti > 0 && (ti * NT - (ti * (ti - 1)) / 2) > tlin) --ti;
  while (((ti + 1) * NT - ((ti + 1) * ti) / 2) <= tlin) ++ti;
  int tj = ti + (tlin - (ti * NT - (ti * (ti - 1)) / 2));
  int i0 = ti * 64, j0 = tj * 64;
  bool diag = (ti == tj);
  const unsigned short* fb = bf + (size_t)feat * B * D;
  const float* sqf = sq + (size_t)feat * B;

  __shared__ alignas(16) unsigned short Ab[64 * 128];
  __shared__ alignas(16) unsigned short Bb[64 * 128];
  __shared__ unsigned int gsw[4][4][HS];
  __shared__ int gA[64], gB[64];
  __shared__ float sA[64], sB[64];

  int tid = threadIdx.x;
  int w = tid >> 6, L = tid & 63, m = L & 15, q = L >> 4;

  // prologue (pre-barrier): zero histograms, cache tile gid/sq in LDS
  {
    unsigned int* gz = (unsigned int*)gsw;
    for (int e = tid; e < 4 * 4 * HS; e += 256) gz[e] = 0;
    if (tid < 64) { gA[tid] = gid[i0 + tid]; sA[tid] = sqf[i0 + tid]; }
    else if (tid < 128) { int r = tid - 64; gB[r] = gid[j0 + r]; sB[r] = sqf[j0 + r]; }
  }

  f32x4 acc[4] = {{0.f,0.f,0.f,0.f},{0.f,0.f,0.f,0.f},{0.f,0.f,0.f,0.f},{0.f,0.f,0.f,0.f}};

  for (int h = 0; h < 2; ++h) {              // K halves of 128
    if (h) __syncthreads();
    for (int e = tid; e < 1024; e += 256) {
      int row = e >> 4, ck = e & 15;
      uint4 v = *(const uint4*)(fb + (size_t)(i0 + row) * D + h * 128 + ck * 8);
      *(uint4*)&Ab[row * 128 + ((ck ^ (row & 15)) * 8)] = v;
    }
    if (!diag) {
      for (int e = tid; e < 1024; e += 256) {
        int row = e >> 4, ck = e & 15;
        uint4 v = *(const uint4*)(fb + (size_t)(j0 + row) * D + h * 128 + ck * 8);
        *(uint4*)&Bb[row * 128 + ((ck ^ (row & 15)) * 8)] = v;
      }
    }
    __syncthreads();
    const unsigned short* Bp = diag ? Ab : Bb;
    #pragma unroll
    for (int kk = 0; kk < 4; ++kk) {
      int ar = w * 16 + m;
      bf16x8 aF = *(const bf16x8*)&Ab[ar * 128 + (((kk * 4 + q) ^ (ar & 15)) * 8)];
      #pragma unroll
      for (int c = 0; c < 4; ++c) {
        int br = c * 16 + m;
        bf16x8 bF = *(const bf16x8*)&Bp[br * 128 + (((kk * 4 + q) ^ (br & 15)) * 8)];
        acc[c] = __builtin_amdgcn_mfma_f32_16x16x32_bf16(aF, bF, acc[c], 0, 0, 0);
      }
    }
  }
  // C/D layout (verified m89/m91): col = lane&15, row = (lane>>4)*4 + reg.
  // Wave w / quad q writes only gsw[w][q] -> no barrier needed here.
  #pragma unroll
  for (int c = 0; c < 4; ++c) {
    #pragma unroll
    for (int v = 0; v < 4; ++v) {
      int ri = w * 16 + q * 4 + v;           // row in tile
      int rj = c * 16 + m;                   // col in tile
      int gi = gA[ri], gj = gB[rj];
      if (gi >= 0 && gj >= 0 && !(diag && ri > rj)) {
        float K;
        if (diag && ri == rj) K = 5.f;       // exact diagonal
        else {
          float d = sA[ri] + sB[rj] - 2.f * acc[c][v];
          d = fmaxf(d, 0.f);
          K = __expf(-0.01f * d) + __expf(-0.1f * d) + __expf(-d)
            + __expf(-10.f * d) + __expf(-100.f * d);
        }
        unsigned int kf = (unsigned int)(K * 65536.f + 0.5f);
        int a = min(gi, gj), b = max(gi, gj);
        atomicAdd(&gsw[w][q][a * NG + b], kf);   // ds_add_u32
      }
    }
  }
  __syncthreads();
  if (tid < NG * NG) {
    u64 s = 0;
    #pragma unroll
    for (int ww = 0; ww < 4; ++ww)
      #pragma unroll
      for (int qq = 0; qq < 4; ++qq) s += gsw[ww][qq][tid];
    if (s)   // 64 GSP copies to spread global atomic contention
      atomicAdd(&GSP[((size_t)(blockIdx.x & 63) * 2 + feat) * NG * NG + tid], s);
  }
}

// ----------------------------------------- hsic partials: tr(KL), u^T M v
extern "C" __global__ __launch_bounds__(256) void k_hsic(
    const u64* __restrict__ U64, const u64* __restrict__ M64, u64* SA) {
  __shared__ float red[8];
  __shared__ float ush[32], vsh[D];
  int p = blockIdx.y;
  int k0 = blockIdx.x * 32;
  int t = threadIdx.x;
  vsh[t] = fxToF(U64[(2 * p + 1) * D + t]);
  if (t < 32) ush[t] = fxToF(U64[(2 * p) * D + k0 + t]);
  __syncthreads();
  const u64* Mp = M64 + (size_t)p * D * D;
  float trkl = 0.f, cr = 0.f;
  #pragma unroll 4
  for (int k = 0; k < 32; ++k) {
    float mv = fxToF(Mp[(size_t)(k0 + k) * D + t]);
    trkl += mv * mv;
    cr += ush[k] * mv;
  }
  cr *= vsh[t];
  #pragma unroll
  for (int o = 32; o > 0; o >>= 1) { trkl += __shfl_down(trkl, o); cr += __shfl_down(cr, o); }
  if ((t & 63) == 0) { red[t >> 6] = trkl; red[4 + (t >> 6)] = cr; }
  __syncthreads();
  if (t == 0) gAddFx(&SA[10 + p], red[0] + red[1] + red[2] + red[3]);
  if (t == 64) gAddFx(&SA[12 + p], red[4] + red[5] + red[6] + red[7]);
}

// -------------------------------------------------------- focal + CE losses
__device__ inline float focal_n(const float* x, int n, int tgt,
                                float s_over_n, float oms) {
  float mx = x[0];
  for (int c = 1; c < n; ++c) mx = fmaxf(mx, x[c]);
  float se = 0.f, sx = 0.f;
  for (int c = 0; c < n; ++c) { se += __expf(x[c] - mx); sx += x[c]; }
  float logZ = mx + __logf(se);
  float ce = logZ - oms * x[tgt] - s_over_n * sx;
  float pt = __expf(x[tgt] - logZ);
  float om = 1.f - pt;
  return ce * om * om;
}

extern "C" __global__ __launch_bounds__(256) void k_cls(
    const float* __restrict__ l1, const int* __restrict__ y1,
    const float* __restrict__ l2, const int* __restrict__ y2,
    const float* __restrict__ l3, const int* __restrict__ y3,
    const float* __restrict__ vsv, const float* __restrict__ vst,
    const int* __restrict__ dom, const float* __restrict__ maskf,
    u64* SA, int B) {
  __shared__ float red[4];
  int t = threadIdx.x;
  int r = blockIdx.x * 256 + t;
  float s[5] = {0.f, 0.f, 0.f, 0.f, 0.f};
  if (r < B) {
    float mk = maskf[r];
    if (mk > 0.f) {
      float x[6];
      for (int c = 0; c < 4; ++c) x[c] = l1[r * 4 + c];
      s[0] = focal_n(x, 4, y1[r], 0.1f / 4.f, 0.9f) * mk;
      for (int c = 0; c < 6; ++c) x[c] = l2[r * 6 + c];
      s[1] = focal_n(x, 6, y2[r], 0.1f / 6.f, 0.9f) * mk;
      for (int c = 0; c < 3; ++c) x[c] = l3[r * 3 + c];
      s[2] = focal_n(x, 3, y3[r], 0.1f / 3.f, 0.9f) * mk;
      int d = dom[r];
      for (int c = 0; c < 4; ++c) x[c] = vsv[r * 4 + c];
      {
        float mx = fmaxf(fmaxf(x[0], x[1]), fmaxf(x[2], x[3]));
        float se = __expf(x[0]-mx) + __expf(x[1]-mx) + __expf(x[2]-mx) + __expf(x[3]-mx);
        s[3] = (mx + __logf(se) - x[d]) * mk;
      }
      for (int c = 0; c < 4; ++c) x[c] = vst[r * 4 + c];
      {
        float mx = fmaxf(fmaxf(x[0], x[1]), fmaxf(x[2], x[3]));
        float se = __expf(x[0]-mx) + __expf(x[1]-mx) + __expf(x[2]-mx) + __expf(x[3]-mx);
        s[4] = (mx + __logf(se) - x[d]) * mk;
      }
    }
  }
  for (int k = 0; k < 5; ++k) {
    float v = s[k];
    #pragma unroll
    for (int o = 32; o > 0; o >>= 1) v += __shfl_down(v, o);
    __syncthreads();
    if ((t & 63) == 0) red[t >> 6] = v;
    __syncthreads();
    if (t == 0) gAddFx(&SA[k], red[0] + red[1] + red[2] + red[3]);
  }
}

// ------------------------------------------------------------- recon MSE sums
extern "C" __global__ __launch_bounds__(256) void k_recon(
    const float* __restrict__ ir, const float* __restrict__ io,
    const float* __restrict__ tr_, const float* __restrict__ to,
    u64* SA, int N4) {
  __shared__ float red[4];
  int j = blockIdx.y;
  const float4* A  = (const float4*)(j ? tr_ : ir);
  const float4* Bp = (const float4*)(j ? to : io);
  int t = threadIdx.x;
  float acc = 0.f;
  for (int idx = blockIdx.x * 256 + t; idx < N4; idx += gridDim.x * 256) {
    float4 a = A[idx], b = Bp[idx];
    float dx = a.x-b.x, dy = a.y-b.y, dz = a.z-b.z, dw = a.w-b.w;
    acc += dx*dx + dy*dy + dz*dz + dw*dw;
  }
  #pragma unroll
  for (int o = 32; o > 0; o >>= 1) acc += __shfl_down(acc, o);
  if ((t & 63) == 0) red[t >> 6] = acc;
  __syncthreads();
  if (t == 0) gAddFx(&SA[6 + j], red[0] + red[1] + red[2] + red[3]);
}

// ----------------------------------------------------------------- finalize
extern "C" __global__ __launch_bounds__(256) void k_final(
    const u64* SA, const u64* GCU, const u64* GSP,
    const u64* U64, float* out, int B) {
  __shared__ float red[8];
  __shared__ float gssh[2 * NG * NG];
  int t = threadIdx.x;
  for (int e = t; e < 2 * NG * NG; e += 256) {
    u64 ssum = 0;
    int f = e >> 8, idx = e & 255;
    for (int cpy = 0; cpy < 64; ++cpy)
      ssum += GSP[((size_t)cpy * 2 + f) * NG * NG + idx];
    gssh[e] = (float)((double)ssum * (1.0 / 65536.0));
  }
  __syncthreads();

  float n = (float)B;
  float hs[2];
  for (int p = 0; p < 2; ++p) {
    float ut = fxToF(U64[(2 * p) * D + t]);
    float vt = fxToF(U64[(2 * p + 1) * D + t]);
    float uu = ut * ut, vv = vt * vt;
    #pragma unroll
    for (int o = 32; o > 0; o >>= 1) { uu += __shfl_down(uu, o); vv += __shfl_down(vv, o); }
    __syncthreads();
    if ((t & 63) == 0) { red[t >> 6] = uu; red[4 + (t >> 6)] = vv; }
    __syncthreads();
    float uus = red[0] + red[1] + red[2] + red[3];
    float vvs = red[4] + red[5] + red[6] + red[7];
    float trkl = (float)((double)(long long)SA[10 + p] * (double)IFX32);
    float cr   = (float)((double)(long long)SA[12 + p] * (double)IFX32);
    hs[p] = (trkl - (2.f / n) * cr + uus * vvs / (n * n))
          / ((n - 1.f) * (n - 1.f));
  }
  if (t == 0) {
    float msum = fmaxf((float)SA[5], 1.f);
    float f1 = fxToF(SA[0]) / msum;
    float f2 = fxToF(SA[1]) / msum;
    float f3 = fxToF(SA[2]) / msum;
    float cesv = fxToF(SA[3]) / msum;
    float cest = fxToF(SA[4]) / msum;
    float mmd[2];
    for (int f = 0; f < 2; ++f) {
      float loss = 0.f, cntv = 0.f;
      for (int lab = 0; lab < 4; ++lab)
        for (int d1 = 0; d1 < 4; ++d1)
          for (int d2 = d1 + 1; d2 < 4; ++d2) {
            int a = lab * 4 + d1, b = lab * 4 + d2;
            float n1 = (float)GCU[a], n2 = (float)GCU[b];
            if (n1 > 1.f && n2 > 1.f) {
              // canonical bins: S[a][a] = 2*bin - 5*n_a ; S[a][b] = bin (a<b)
              float g11 = 2.f * gssh[f * 256 + a * NG + a] - 5.f * n1;
              float g22 = 2.f * gssh[f * 256 + b * NG + b] - 5.f * n2;
              float g12 = gssh[f * 256 + a * NG + b];
              loss += g11 / (fmaxf(n1, 1.f) * fmaxf(n1, 1.f))
                    + g22 / (fmaxf(n2, 1.f) * fmaxf(n2, 1.f))
                    - 2.f * g12 / fmaxf(n1 * n2, 1.f);
              cntv += 1.f;
            }
          }
      mmd[f] = loss / fmaxf(cntv, 1.f);
    }
    double rs = ((double)(long long)SA[6] + (double)(long long)SA[7])
              * (double)IFX32;
    float recon = (float)(rs / ((double)B * (double)H));
    float total = 0.4f * f1 + 0.3f * f2 + 0.3f * f3
                + 0.1f * (cesv + cest + mmd[0] + mmd[1])
                + 0.1f * (hs[0] + hs[1])
                + recon;
    out[0] = total;
  }
}

// ---------------------------------------------------------------------------
extern "C" void kernel_launch(void* const* d_in, const int* in_sizes, int n_in,
                              void* d_out, int out_size, void* d_ws, size_t ws_size,
                              hipStream_t stream) {
  const float* l1  = (const float*)d_in[0];
  const int*   y1  = (const int*)d_in[1];
  const float* l2  = (const float*)d_in[2];
  const int*   y2  = (const int*)d_in[3];
  const float* l3  = (const float*)d_in[4];
  const int*   y3  = (const int*)d_in[5];
  const float* cv  = (const float*)d_in[6];
  const float* sv  = (const float*)d_in[7];
  const float* ct  = (const float*)d_in[8];
  const float* st  = (const float*)d_in[9];
  const float* vsv = (const float*)d_in[10];
  const float* vst = (const float*)d_in[11];
  const int*   dom = (const int*)d_in[12];
  const void*  mask= d_in[13];
  const float* ir  = (const float*)d_in[14];
  const float* io  = (const float*)d_in[15];
  const float* trc = (const float*)d_in[16];
  const float* to  = (const float*)d_in[17];
  int B = in_sizes[1];                        // 4096

  // workspace layout: u64 accumulators first (all zeroed), then scratch
  u64* SA  = (u64*)d_ws;                      // 32 slots
  u64* GCU = SA + 32;                         // 16 group counts
  u64* U64 = GCU + 16;                        // 4*256  (i64 fx 2^32)
  u64* M64 = U64 + 4 * D;                     // 2*256*256 (i64 fx 2^32)
  u64* GSP = M64 + 2 * D * D;                 // 64*2*256 (u64 fx 2^16)
  u64* zend = GSP + 64 * 2 * NG * NG;
  size_t zeroBytes = (size_t)((char*)zend - (char*)d_ws);
  float* maskf = (float*)zend;                // B
  int*   gid   = (int*)(maskf + B);           // B
  float* sq    = (float*)(gid + B);           // 2*B
  float* inv   = sq + 2 * B;                  // 4*B
  unsigned short* bf = (unsigned short*)(inv + 4 * B); // 2*B*D bf16

  hipMemsetAsync(d_ws, 0, zeroBytes, stream);
  k_detect<<<1, 256, 0, stream>>>((const unsigned char*)mask, B, SA);
  k_prep<<<B / 256, 256, 0, stream>>>(mask, y1, dom, SA, GCU, maskf, gid, B);
  k_rowstats<<<dim3(B / 4, 4), 256, 0, stream>>>(cv, sv, ct, st, bf, sq, inv, B);
  k_u<<<dim3(B / 64, 4), 256, 0, stream>>>(cv, sv, ct, st, inv, U64, B);
  k_m<<<dim3(16, 8, 2), 256, 0, stream>>>(cv, sv, ct, st, inv, M64, B);
  int NT = B / 64;
  k_mmd<<<dim3(NT * (NT + 1) / 2, 2), 256, 0, stream>>>(bf, sq, gid, GSP, B);
  k_hsic<<<dim3(8, 2), 256, 0, stream>>>(U64, M64, SA);
  k_cls<<<B / 256, 256, 0, stream>>>(l1, y1, l2, y2, l3, y3, vsv, vst, dom,
                                     maskf, SA, B);
  k_recon<<<dim3(1024, 2), 256, 0, stream>>>(ir, io, trc, to, SA, B * H / 4);
  k_final<<<1, 256, 0, stream>>>(SA, GCU, GSP, U64, (float*)d_out, B);
}

// Round 4
// 253.333 us; speedup vs baseline: 2.2553x; 1.2468x over previous
//
#include <hip/hip_runtime.h>
#include <hip/hip_bf16.h>

// ---------------------------------------------------------------------------
// CausalCrisisLoss on MI355X.  R4: collapse 11 graph nodes -> 5.
//  * k_pre  = detect+prep+cls (role A) | rowstats+u (role B) | recon (role C)
//  * k_big  = k_m GEMM blocks (role M, first 512) | mmd tiles (role T)
//             - mmd: per-wave hist [4][264] -> LDS 38KB -> 4 blocks/CU
//             - epilogue: gA/sA hoisted, canonical min/max bins
//  * k_hsic, k_final unchanged.
// No float atomics anywhere (CAS-loop hazard): u32 ds_add + i64 fx2^32 /
// u64 fx2^16 native global atomics. Bit-deterministic across replays.
// ---------------------------------------------------------------------------

typedef short bf16x8 __attribute__((ext_vector_type(8)));
typedef float f32x4 __attribute__((ext_vector_type(4)));
typedef unsigned long long u64;
typedef unsigned int u32;

static constexpr int D = 256;
static constexpr int H = 768;
static constexpr int NG = 16;
static constexpr float FX32 = 4294967296.f;
static constexpr float IFX32 = 2.3283064365386963e-10f;

__device__ inline void gAddFx(u64* p, float v) {
  long long q = (long long)llroundf(v * FX32);
  atomicAdd(p, (u64)q);                           // native global_atomic_add_x2
}
__device__ inline float fxToF(u64 v) { return (float)(long long)v * IFX32; }

__device__ inline float focal_n(const float* x, int n, int tgt,
                                float s_over_n, float oms) {
  float mx = x[0];
  for (int c = 1; c < n; ++c) mx = fmaxf(mx, x[c]);
  float se = 0.f, sx = 0.f;
  for (int c = 0; c < n; ++c) { se += __expf(x[c] - mx); sx += x[c]; }
  float logZ = mx + __logf(se);
  float ce = logZ - oms * x[tgt] - s_over_n * sx;
  float pt = __expf(x[tgt] - logZ);
  float om = 1.f - pt;
  return ce * om * om;
}

// ============================================================== k_pre (fused)
// role A [0,NA):        mode-detect (local) + maskf/gid/counts + cls losses
// role B [NA,NA+NB):    per-row norms, bf16 copy, sq, inv, u-partials
// role C [NA+NB, +NC):  recon MSE
extern "C" __global__ __launch_bounds__(256) void k_pre(
    const void* __restrict__ mask, const int* __restrict__ y1,
    const int* __restrict__ dom,
    const float* __restrict__ l1, const float* __restrict__ l2,
    const float* __restrict__ l3, const int* __restrict__ y2,
    const int* __restrict__ y3,
    const float* __restrict__ vsv, const float* __restrict__ vst,
    const float* __restrict__ cv, const float* __restrict__ sv,
    const float* __restrict__ ct, const float* __restrict__ st,
    const float* __restrict__ ir, const float* __restrict__ io,
    const float* __restrict__ trc, const float* __restrict__ to,
    u64* SA, u64* GCU, u64* U64,
    int* gid, float* sq, float* inv, unsigned short* bf,
    int B, int N4, int NA, int NB) {
  __shared__ u32 sh3[3];
  __shared__ u32 cnt[NG];
  __shared__ int redi[4];
  __shared__ float redf[4];
  int bid = blockIdx.x;
  int t = threadIdx.x;

  if (bid < NA) {
    // ---------------- role A: detect + prep + cls ----------------
    if (t < 3) sh3[t] = 0;
    if (t < NG) cnt[t] = 0;
    __syncthreads();
    // mode detect: scan first B BYTES (in-bounds for u8/i32/f32)
    u32 a = 0, b2 = 0, cd = 0;
    if (t * 16 + 15 < B) {
      uint4 wv = ((const uint4*)mask)[t];
      u32 ws[4] = {wv.x, wv.y, wv.z, wv.w};
      #pragma unroll
      for (int j = 0; j < 4; ++j) {
        a |= ws[j] & 0xffu; b2 |= ws[j] & 0xff00u; cd |= ws[j] & 0xffff0000u;
      }
    }
    if (a) atomicOr(&sh3[0], 1u);
    if (b2) atomicOr(&sh3[1], 1u);
    if (cd) atomicOr(&sh3[2], 1u);
    __syncthreads();
    int mode;
    if ((sh3[1] | sh3[2]) == 0) mode = 0;          // int32 0/1
    else if (sh3[0] == 0 && sh3[1] == 0) mode = 1; // f32
    else mode = 2;                                 // u8
    int r = bid * 256 + t;
    int mi = 0;
    float s[5] = {0.f, 0.f, 0.f, 0.f, 0.f};
    if (r < B) {
      if (mode == 0)      mi = ((const int*)mask)[r] ? 1 : 0;
      else if (mode == 1) mi = (((const float*)mask)[r] != 0.f) ? 1 : 0;
      else                mi = ((const unsigned char*)mask)[r] ? 1 : 0;
      int g = -1;
      if (mi) { g = y1[r] * 4 + dom[r]; atomicAdd(&cnt[g], 1u); }
      gid[r] = g;
      if (mi) {
        float x[6];
        for (int c = 0; c < 4; ++c) x[c] = l1[r * 4 + c];
        s[0] = focal_n(x, 4, y1[r], 0.1f / 4.f, 0.9f);
        for (int c = 0; c < 6; ++c) x[c] = l2[r * 6 + c];
        s[1] = focal_n(x, 6, y2[r], 0.1f / 6.f, 0.9f);
        for (int c = 0; c < 3; ++c) x[c] = l3[r * 3 + c];
        s[2] = focal_n(x, 3, y3[r], 0.1f / 3.f, 0.9f);
        int d = dom[r];
        for (int c = 0; c < 4; ++c) x[c] = vsv[r * 4 + c];
        {
          float mx = fmaxf(fmaxf(x[0], x[1]), fmaxf(x[2], x[3]));
          float se = __expf(x[0]-mx)+__expf(x[1]-mx)+__expf(x[2]-mx)+__expf(x[3]-mx);
          s[3] = mx + __logf(se) - x[d];
        }
        for (int c = 0; c < 4; ++c) x[c] = vst[r * 4 + c];
        {
          float mx = fmaxf(fmaxf(x[0], x[1]), fmaxf(x[2], x[3]));
          float se = __expf(x[0]-mx)+__expf(x[1]-mx)+__expf(x[2]-mx)+__expf(x[3]-mx);
          s[4] = mx + __logf(se) - x[d];
        }
      }
    }
    int v = mi;
    #pragma unroll
    for (int o = 32; o > 0; o >>= 1) v += __shfl_down(v, o);
    if ((t & 63) == 0) redi[t >> 6] = v;
    __syncthreads();
    if (t == 0) atomicAdd(&SA[5], (u64)(redi[0] + redi[1] + redi[2] + redi[3]));
    if (t < NG && cnt[t]) atomicAdd(&GCU[t], (u64)cnt[t]);
    for (int k = 0; k < 5; ++k) {
      float x = s[k];
      #pragma unroll
      for (int o = 32; o > 0; o >>= 1) x += __shfl_down(x, o);
      __syncthreads();
      if ((t & 63) == 0) redf[t >> 6] = x;
      __syncthreads();
      if (t == 0) gAddFx(&SA[k], redf[0] + redf[1] + redf[2] + redf[3]);
    }
  } else if (bid < NA + NB) {
    // ---------------- role B: rowstats + u ----------------
    int b = bid - NA;
    int f = b >> 6;                          // 0..3  (cv, sv, ct, st)
    int rb = b & 63;
    const float* p = (f == 0) ? cv : (f == 1) ? sv : (f == 2) ? ct : st;
    int w = t >> 6, L = t & 63;
    float up0 = 0.f, up1 = 0.f, up2 = 0.f, up3 = 0.f;
    for (int k = 0; k < 16; ++k) {
      int r = rb * 64 + w * 16 + k;
      float4 v = ((const float4*)(p + (size_t)r * D))[L];
      float ss = v.x * v.x + v.y * v.y + v.z * v.z + v.w * v.w;
      #pragma unroll
      for (int o = 32; o > 0; o >>= 1) ss += __shfl_down(ss, o);
      ss = __shfl(ss, 0);
      float iv = 1.f / fmaxf(sqrtf(ss), 1e-12f);
      if ((f & 1) == 0) {
        int fi = f >> 1;
        alignas(8) __hip_bfloat16 hb[4];
        hb[0] = __float2bfloat16(v.x); hb[1] = __float2bfloat16(v.y);
        hb[2] = __float2bfloat16(v.z); hb[3] = __float2bfloat16(v.w);
        *(uint2*)(bf + ((size_t)fi * B + r) * D + L * 4) = *(uint2*)hb;
        if (L == 0) sq[fi * B + r] = ss;
      }
      if (L == 0) inv[f * B + r] = iv;
      up0 += v.x * iv; up1 += v.y * iv; up2 += v.z * iv; up3 += v.w * iv;
    }
    u64* Uf = U64 + f * D + 4 * L;
    gAddFx(Uf + 0, up0); gAddFx(Uf + 1, up1);
    gAddFx(Uf + 2, up2); gAddFx(Uf + 3, up3);
  } else {
    // ---------------- role C: recon ----------------
    int cidx = bid - (NA + NB);
    int j = cidx >> 8;                       // 0/1: img / txt
    int cb = cidx & 255;
    const float4* A  = (const float4*)(j ? trc : ir);
    const float4* Bp = (const float4*)(j ? to : io);
    float acc = 0.f;
    for (int idx = cb * 256 + t; idx < N4; idx += 256 * 256) {
      float4 a = A[idx], b = Bp[idx];
      float dx = a.x-b.x, dy = a.y-b.y, dz = a.z-b.z, dw = a.w-b.w;
      acc += dx*dx + dy*dy + dz*dz + dw*dw;
    }
    #pragma unroll
    for (int o = 32; o > 0; o >>= 1) acc += __shfl_down(acc, o);
    if ((t & 63) == 0) redf[t >> 6] = acc;
    __syncthreads();
    if (t == 0) gAddFx(&SA[6 + j], redf[0] + redf[1] + redf[2] + redf[3]);
  }
}

// ============================================================== k_big (fused)
// role M [0,512): M = Chat^T Shat partial GEMM  (hidden under mmd waves)
// role T [512, 512+2*2080): 64x64 Gram tiles + multi-gamma RBF + group bins
extern "C" __global__ __launch_bounds__(256) void k_big(
    const float* __restrict__ cv, const float* __restrict__ sv,
    const float* __restrict__ ct, const float* __restrict__ st,
    const float* __restrict__ inv, u64* M64,
    const unsigned short* __restrict__ bf, const float* __restrict__ sq,
    const int* __restrict__ gid, u64* GSP, int B) {
  __shared__ __align__(16) char smem[38016];
  int bid = blockIdx.x;
  int tid = threadIdx.x;

  if (bid < 512) {
    // ---------------- role M ----------------
    float (*lc)[16] = (float(*)[16])smem;         // 16 KB
    float* lis = (float*)(smem + 16384);          // 1 KB
    int p = bid >> 8;
    int a0 = ((bid >> 4) & 15) * 16;
    int i0 = (bid & 15) * 256;                    // clen = 256
    const float* c = p ? ct : cv;
    const float* s = p ? st : sv;
    const float* ic = inv + (2 * p) * B;
    const float* is = inv + (2 * p + 1) * B;
    int t = tid;
    if (t < 256) lis[t] = is[i0 + t];
    for (int e = t; e < 256 * 16; e += 256) {
      int i = e >> 4, rr = e & 15;
      lc[i][rr] = c[(size_t)(i0 + i) * D + a0 + rr] * ic[i0 + i];
    }
    __syncthreads();
    float4 acc[4];
    #pragma unroll
    for (int r = 0; r < 4; ++r) acc[r] = make_float4(0.f, 0.f, 0.f, 0.f);
    #pragma unroll 8
    for (int i = 0; i < 256; ++i) {
      float svv = s[(size_t)(i0 + i) * D + t] * lis[i];
      const float4* lr = (const float4*)lc[i];
      #pragma unroll
      for (int r = 0; r < 4; ++r) {
        float4 c4 = lr[r];
        acc[r].x += c4.x * svv; acc[r].y += c4.y * svv;
        acc[r].z += c4.z * svv; acc[r].w += c4.w * svv;
      }
    }
    u64* Mp = M64 + (size_t)p * D * D;
    #pragma unroll
    for (int r = 0; r < 4; ++r) {
      gAddFx(&Mp[(a0 + 4 * r + 0) * D + t], acc[r].x);
      gAddFx(&Mp[(a0 + 4 * r + 1) * D + t], acc[r].y);
      gAddFx(&Mp[(a0 + 4 * r + 2) * D + t], acc[r].z);
      gAddFx(&Mp[(a0 + 4 * r + 3) * D + t], acc[r].w);
    }
    return;
  }

  // ---------------- role T: mmd tile ----------------
  unsigned short* Ab = (unsigned short*)smem;               // 16 KB
  unsigned short* Bb = (unsigned short*)(smem + 16384);     // 16 KB
  u32 (*gsw)[264] = (u32(*)[264])(smem + 32768);            // 4224 B
  int*   gA = (int*)(smem + 36992);                         // 256 B
  int*   gB = gA + 64;                                      // 256 B
  float* sA = (float*)(gB + 64);                            // 256 B
  float* sB = sA + 64;                                      // 256 B

  int idx2 = bid - 512;
  int feat = idx2 & 1;
  int tlin = idx2 >> 1;
  int NT = B / 64;
  float tf = (float)tlin;
  int ti = (int)((2.f * NT + 1.f -
                  sqrtf((2.f * NT + 1.f) * (2.f * NT + 1.f) - 8.f * tf)) * 0.5f);
  while (ti > 0 && (ti * NT - (ti * (ti - 1)) / 2) > tlin) --ti;
  while (((ti + 1) * NT - ((ti + 1) * ti) / 2) <= tlin) ++ti;
  int tj = ti + (tlin - (ti * NT - (ti * (ti - 1)) / 2));
  int i0 = ti * 64, j0 = tj * 64;
  bool diag = (ti == tj);
  const unsigned short* fb = bf + (size_t)feat * B * D;
  const float* sqf = sq + (size_t)feat * B;

  int w = tid >> 6, L = tid & 63, m = L & 15, q = L >> 4;

  { // prologue (pre-barrier): zero hist, cache tile gid/sq
    u32* gz = (u32*)gsw;
    for (int e = tid; e < 4 * 264; e += 256) gz[e] = 0;
    if (tid < 64) { gA[tid] = gid[i0 + tid]; sA[tid] = sqf[i0 + tid]; }
    else if (tid < 128) { int r = tid - 64; gB[r] = gid[j0 + r]; sB[r] = sqf[j0 + r]; }
  }

  f32x4 acc[4] = {{0.f,0.f,0.f,0.f},{0.f,0.f,0.f,0.f},{0.f,0.f,0.f,0.f},{0.f,0.f,0.f,0.f}};

  for (int h = 0; h < 2; ++h) {              // K halves of 128
    if (h) __syncthreads();
    for (int e = tid; e < 1024; e += 256) {
      int row = e >> 4, ck = e & 15;
      uint4 v = *(const uint4*)(fb + (size_t)(i0 + row) * D + h * 128 + ck * 8);
      *(uint4*)&Ab[row * 128 + ((ck ^ (row & 15)) * 8)] = v;
    }
    if (!diag) {
      for (int e = tid; e < 1024; e += 256) {
        int row = e >> 4, ck = e & 15;
        uint4 v = *(const uint4*)(fb + (size_t)(j0 + row) * D + h * 128 + ck * 8);
        *(uint4*)&Bb[row * 128 + ((ck ^ (row & 15)) * 8)] = v;
      }
    }
    __syncthreads();
    const unsigned short* Bp = diag ? Ab : Bb;
    #pragma unroll
    for (int kk = 0; kk < 4; ++kk) {
      int ar = w * 16 + m;
      bf16x8 aF = *(const bf16x8*)&Ab[ar * 128 + (((kk * 4 + q) ^ (ar & 15)) * 8)];
      #pragma unroll
      for (int c = 0; c < 4; ++c) {
        int br = c * 16 + m;
        bf16x8 bF = *(const bf16x8*)&Bp[br * 128 + (((kk * 4 + q) ^ (br & 15)) * 8)];
        acc[c] = __builtin_amdgcn_mfma_f32_16x16x32_bf16(aF, bF, acc[c], 0, 0, 0);
      }
    }
  }
  // epilogue: C/D layout col=lane&15, row=(lane>>4)*4+reg (m89/m91).
  // Hoist row-side lookups; wave w writes only gsw[w] -> no barrier needed.
  int ri0 = w * 16 + q * 4;
  int gi0 = gA[ri0], gi1 = gA[ri0+1], gi2 = gA[ri0+2], gi3 = gA[ri0+3];
  float si0 = sA[ri0], si1 = sA[ri0+1], si2 = sA[ri0+2], si3 = sA[ri0+3];
  int giv[4] = {gi0, gi1, gi2, gi3};
  float siv[4] = {si0, si1, si2, si3};
  #pragma unroll
  for (int c = 0; c < 4; ++c) {
    int rj = c * 16 + m;
    int gj = gB[rj];
    float sb = sB[rj];
    #pragma unroll
    for (int v = 0; v < 4; ++v) {
      int ri = ri0 + v;
      int gi = giv[v];
      if (gi >= 0 && gj >= 0 && !(diag && ri > rj)) {
        float K;
        if (diag && ri == rj) K = 5.f;
        else {
          float d = fmaxf(siv[v] + sb - 2.f * acc[c][v], 0.f);
          K = __expf(-0.01f * d) + __expf(-0.1f * d) + __expf(-d)
            + __expf(-10.f * d) + __expf(-100.f * d);
        }
        u32 kf = (u32)(K * 65536.f + 0.5f);
        int a = min(gi, gj), b = max(gi, gj);
        atomicAdd(&gsw[w][a * NG + b], kf);   // ds_add_u32
      }
    }
  }
  __syncthreads();
  if (tid < NG * NG) {
    u64 s = (u64)gsw[0][tid] + gsw[1][tid] + gsw[2][tid] + gsw[3][tid];
    if (s)
      atomicAdd(&GSP[((size_t)(tlin & 63) * 2 + feat) * NG * NG + tid], s);
  }
}

// ----------------------------------------- hsic partials: tr(KL), u^T M v
extern "C" __global__ __launch_bounds__(256) void k_hsic(
    const u64* __restrict__ U64, const u64* __restrict__ M64, u64* SA) {
  __shared__ float red[8];
  __shared__ float ush[32], vsh[D];
  int p = blockIdx.y;
  int k0 = blockIdx.x * 32;
  int t = threadIdx.x;
  vsh[t] = fxToF(U64[(2 * p + 1) * D + t]);
  if (t < 32) ush[t] = fxToF(U64[(2 * p) * D + k0 + t]);
  __syncthreads();
  const u64* Mp = M64 + (size_t)p * D * D;
  float trkl = 0.f, cr = 0.f;
  #pragma unroll 4
  for (int k = 0; k < 32; ++k) {
    float mv = fxToF(Mp[(size_t)(k0 + k) * D + t]);
    trkl += mv * mv;
    cr += ush[k] * mv;
  }
  cr *= vsh[t];
  #pragma unroll
  for (int o = 32; o > 0; o >>= 1) { trkl += __shfl_down(trkl, o); cr += __shfl_down(cr, o); }
  if ((t & 63) == 0) { red[t >> 6] = trkl; red[4 + (t >> 6)] = cr; }
  __syncthreads();
  if (t == 0) gAddFx(&SA[10 + p], red[0] + red[1] + red[2] + red[3]);
  if (t == 64) gAddFx(&SA[12 + p], red[4] + red[5] + red[6] + red[7]);
}

// ----------------------------------------------------------------- finalize
extern "C" __global__ __launch_bounds__(256) void k_final(
    const u64* SA, const u64* GCU, const u64* GSP,
    const u64* U64, float* out, int B) {
  __shared__ float red[8];
  __shared__ float gssh[2 * NG * NG];
  int t = threadIdx.x;
  for (int e = t; e < 2 * NG * NG; e += 256) {
    u64 ssum = 0;
    int f = e >> 8, idx = e & 255;
    for (int cpy = 0; cpy < 64; ++cpy)
      ssum += GSP[((size_t)cpy * 2 + f) * NG * NG + idx];
    gssh[e] = (float)((double)ssum * (1.0 / 65536.0));
  }
  __syncthreads();

  float n = (float)B;
  float hs[2];
  for (int p = 0; p < 2; ++p) {
    float ut = fxToF(U64[(2 * p) * D + t]);
    float vt = fxToF(U64[(2 * p + 1) * D + t]);
    float uu = ut * ut, vv = vt * vt;
    #pragma unroll
    for (int o = 32; o > 0; o >>= 1) { uu += __shfl_down(uu, o); vv += __shfl_down(vv, o); }
    __syncthreads();
    if ((t & 63) == 0) { red[t >> 6] = uu; red[4 + (t >> 6)] = vv; }
    __syncthreads();
    float uus = red[0] + red[1] + red[2] + red[3];
    float vvs = red[4] + red[5] + red[6] + red[7];
    float trkl = (float)((double)(long long)SA[10 + p] * (double)IFX32);
    float cr   = (float)((double)(long long)SA[12 + p] * (double)IFX32);
    hs[p] = (trkl - (2.f / n) * cr + uus * vvs / (n * n))
          / ((n - 1.f) * (n - 1.f));
    __syncthreads();
  }
  if (t == 0) {
    float msum = fmaxf((float)SA[5], 1.f);
    float f1 = fxToF(SA[0]) / msum;
    float f2 = fxToF(SA[1]) / msum;
    float f3 = fxToF(SA[2]) / msum;
    float cesv = fxToF(SA[3]) / msum;
    float cest = fxToF(SA[4]) / msum;
    float mmd[2];
    for (int f = 0; f < 2; ++f) {
      float loss = 0.f, cntv = 0.f;
      for (int lab = 0; lab < 4; ++lab)
        for (int d1 = 0; d1 < 4; ++d1)
          for (int d2 = d1 + 1; d2 < 4; ++d2) {
            int a = lab * 4 + d1, b = lab * 4 + d2;
            float n1 = (float)GCU[a], n2 = (float)GCU[b];
            if (n1 > 1.f && n2 > 1.f) {
              float g11 = 2.f * gssh[f * 256 + a * NG + a] - 5.f * n1;
              float g22 = 2.f * gssh[f * 256 + b * NG + b] - 5.f * n2;
              float g12 = gssh[f * 256 + a * NG + b];
              loss += g11 / (fmaxf(n1, 1.f) * fmaxf(n1, 1.f))
                    + g22 / (fmaxf(n2, 1.f) * fmaxf(n2, 1.f))
                    - 2.f * g12 / fmaxf(n1 * n2, 1.f);
              cntv += 1.f;
            }
          }
      mmd[f] = loss / fmaxf(cntv, 1.f);
    }
    double rs = ((double)(long long)SA[6] + (double)(long long)SA[7])
              * (double)IFX32;
    float recon = (float)(rs / ((double)B * (double)H));
    float total = 0.4f * f1 + 0.3f * f2 + 0.3f * f3
                + 0.1f * (cesv + cest + mmd[0] + mmd[1])
                + 0.1f * (hs[0] + hs[1])
                + recon;
    out[0] = total;
  }
}

// ---------------------------------------------------------------------------
extern "C" void kernel_launch(void* const* d_in, const int* in_sizes, int n_in,
                              void* d_out, int out_size, void* d_ws, size_t ws_size,
                              hipStream_t stream) {
  const float* l1  = (const float*)d_in[0];
  const int*   y1  = (const int*)d_in[1];
  const float* l2  = (const float*)d_in[2];
  const int*   y2  = (const int*)d_in[3];
  const float* l3  = (const float*)d_in[4];
  const int*   y3  = (const int*)d_in[5];
  const float* cv  = (const float*)d_in[6];
  const float* sv  = (const float*)d_in[7];
  const float* ct  = (const float*)d_in[8];
  const float* st  = (const float*)d_in[9];
  const float* vsv = (const float*)d_in[10];
  const float* vst = (const float*)d_in[11];
  const int*   dom = (const int*)d_in[12];
  const void*  mask= d_in[13];
  const float* ir  = (const float*)d_in[14];
  const float* io  = (const float*)d_in[15];
  const float* trc = (const float*)d_in[16];
  const float* to  = (const float*)d_in[17];
  int B = in_sizes[1];                        // 4096

  // workspace: u64 accumulators (zeroed) then scratch
  u64* SA  = (u64*)d_ws;                      // 32 slots
  u64* GCU = SA + 32;                         // 16
  u64* U64 = GCU + 16;                        // 4*256
  u64* M64 = U64 + 4 * D;                     // 2*256*256
  u64* GSP = M64 + 2 * D * D;                 // 64*2*256
  u64* zend = GSP + 64 * 2 * NG * NG;
  size_t zeroBytes = (size_t)((char*)zend - (char*)d_ws);
  int*   gid = (int*)zend;                    // B
  float* sq  = (float*)(gid + B);             // 2*B
  float* inv = sq + 2 * B;                    // 4*B
  unsigned short* bf = (unsigned short*)(inv + 4 * B); // 2*B*D bf16

  int NA = B / 256;                           // 16  prep+cls blocks
  int NB = 4 * (B / 64);                      // 256 rowstats+u blocks
  int NC = 512;                               // recon blocks (256 per half)
  int N4 = B * H / 4;

  hipMemsetAsync(d_ws, 0, zeroBytes, stream);
  k_pre<<<NA + NB + NC, 256, 0, stream>>>(
      mask, y1, dom, l1, l2, l3, y2, y3, vsv, vst,
      cv, sv, ct, st, ir, io, trc, to,
      SA, GCU, U64, gid, sq, inv, bf, B, N4, NA, NB);
  int NT = B / 64;
  int nmmd = 2 * (NT * (NT + 1) / 2);
  k_big<<<512 + nmmd, 256, 0, stream>>>(cv, sv, ct, st, inv, M64,
                                        bf, sq, gid, GSP, B);
  k_hsic<<<dim3(8, 2), 256, 0, stream>>>(U64, M64, SA);
  k_final<<<1, 256, 0, stream>>>(SA, GCU, GSP, U64, (float*)d_out, B);
}